// Round 4
// baseline (932.406 us; speedup 1.0000x reference)
//
#include <hip/hip_runtime.h>
#include <math.h>

#define SEQ   8192
#define VR    80          // row elems per lane held in VGPRs
#define F4R   20          // = VR/4 float4 groups in regs
#define F4L   12          // float4 groups in LDS (48 elems/lane, 12 KB/wave)
// VR + 4*F4L = 128 elems/lane * 64 lanes = 8192 = SEQ

__device__ __forceinline__ float wave_sum(float x) {
    #pragma unroll
    for (int off = 32; off > 0; off >>= 1)
        x += __shfl_xor(x, off, 64);
    return x;
}

// One wave per block per row. No barriers anywhere: reductions are intra-wave
// shuffles; the LDS slice is strictly same-lane (lane i writes/reads only
// lw4[j*64+i]), so ordering is plain within-thread dependency. 80 elems/lane
// in registers (fits under the 128-VGPR cap -> no scratch spill, unlike R3's
// w[128]) + 48 elems/lane in LDS. 12 KB LDS/block -> ~13 resident rows/CU of
// independent serial chains vs R1's ~3.3.
__global__ __launch_bounds__(64, 4) void normalizer_kernel(
        const float* __restrict__ score,
        const int*   __restrict__ mask,
        float*       __restrict__ out)
{
    const int lane = threadIdx.x;          // 0..63
    const int row  = blockIdx.x;

    __shared__ float4 lw4[F4L * 64];       // 12 KB

    constexpr double L2E = 1.4426950408889634;
    const float cf = (float)(L2E / 0.3);   // score -> w = score*log2e/0.3

    const float4* __restrict__ s4 = (const float4*)(score + (size_t)row * SEQ);
    const int4*   __restrict__ m4 = (const int4*)(mask  + (size_t)row * SEQ);

    float w[VR];
    float cntf = 0.f;
    #pragma unroll
    for (int j = 0; j < F4R; ++j) {
        float4 s = s4[j * 64 + lane];
        int4   m = m4[j * 64 + lane];
        w[4*j+0] = m.x ? s.x * cf : -INFINITY;
        w[4*j+1] = m.y ? s.y * cf : -INFINITY;
        w[4*j+2] = m.z ? s.z * cf : -INFINITY;
        w[4*j+3] = m.w ? s.w * cf : -INFINITY;
        cntf += (float)((m.x != 0) + (m.y != 0) + (m.z != 0) + (m.w != 0));
    }
    #pragma unroll
    for (int j = 0; j < F4L; ++j) {
        float4 s = s4[(F4R + j) * 64 + lane];
        int4   m = m4[(F4R + j) * 64 + lane];
        float4 t;
        t.x = m.x ? s.x * cf : -INFINITY;
        t.y = m.y ? s.y * cf : -INFINITY;
        t.z = m.z ? s.z * cf : -INFINITY;
        t.w = m.w ? s.w * cf : -INFINITY;
        lw4[j * 64 + lane] = t;
        cntf += (float)((m.x != 0) + (m.y != 0) + (m.z != 0) + (m.w != 0));
    }

    const float k   = 0.1f * wave_sum(cntf);
    const float l2k = __builtin_amdgcn_logf(k);   // v_log_f32 = log2
    const float rk  = 1.0f / k;

    // b = -relu(score+a) => score+b = min(score,-a); NA = -a in w-domain.
    float NA  = INFINITY;
    float cp  = 0.075f;        // 0.3/theta_t at t=0 (theta0=4)
    float inv = 13.333334f;    // theta_t/0.3

    for (int t = 0; t < 8; ++t) {          // annealing, theta unclamped
        float a0 = 0.f, a1 = 0.f, a2 = 0.f, a3 = 0.f;
        #pragma unroll
        for (int j = 0; j < VR; j += 4) {
            a0 += __builtin_amdgcn_exp2f(fminf(w[j+0], NA) * cp);
            a1 += __builtin_amdgcn_exp2f(fminf(w[j+1], NA) * cp);
            a2 += __builtin_amdgcn_exp2f(fminf(w[j+2], NA) * cp);
            a3 += __builtin_amdgcn_exp2f(fminf(w[j+3], NA) * cp);
        }
        #pragma unroll
        for (int j = 0; j < F4L; ++j) {
            float4 t4 = lw4[j * 64 + lane];
            a0 += __builtin_amdgcn_exp2f(fminf(t4.x, NA) * cp);
            a1 += __builtin_amdgcn_exp2f(fminf(t4.y, NA) * cp);
            a2 += __builtin_amdgcn_exp2f(fminf(t4.z, NA) * cp);
            a3 += __builtin_amdgcn_exp2f(fminf(t4.w, NA) * cp);
        }
        const float s = wave_sum((a0 + a1) + (a2 + a3));
        NA = inv * (__builtin_amdgcn_logf(s + 1e-20f) - l2k);
        cp  *= 1.4285715f;     // /0.7
        inv *= 0.7f;
    }

    // Switch to e = exp2(w): exp2(min(w,NA)) = min(e,eNA) (monotone).
    #pragma unroll
    for (int j = 0; j < VR; ++j)
        w[j] = __builtin_amdgcn_exp2f(w[j]);
    #pragma unroll
    for (int j = 0; j < F4L; ++j) {
        float4 t4 = lw4[j * 64 + lane];
        t4.x = __builtin_amdgcn_exp2f(t4.x);   // masked -inf -> 0
        t4.y = __builtin_amdgcn_exp2f(t4.y);
        t4.z = __builtin_amdgcn_exp2f(t4.z);
        t4.w = __builtin_amdgcn_exp2f(t4.w);
        lw4[j * 64 + lane] = t4;
    }
    float eNA = __builtin_amdgcn_exp2f(NA);

    // t = 8..19: theta = 0.3. s = sum(min(e,eNA)); eNA' = (s+eps)/k. No exps.
    for (int t = 8; t < 20; ++t) {
        float a0 = 0.f, a1 = 0.f, a2 = 0.f, a3 = 0.f;
        #pragma unroll
        for (int j = 0; j < VR; j += 4) {
            a0 += fminf(w[j+0], eNA);
            a1 += fminf(w[j+1], eNA);
            a2 += fminf(w[j+2], eNA);
            a3 += fminf(w[j+3], eNA);
        }
        #pragma unroll
        for (int j = 0; j < F4L; ++j) {
            float4 t4 = lw4[j * 64 + lane];
            a0 += fminf(t4.x, eNA);
            a1 += fminf(t4.y, eNA);
            a2 += fminf(t4.z, eNA);
            a3 += fminf(t4.w, eNA);
        }
        const float s = wave_sum((a0 + a1) + (a2 + a3));
        eNA = (s + 1e-20f) * rk;
    }

    // gamma = min(e,eNA)/eNA; masked e=0 -> 0.
    const float r = 1.0f / eNA;
    float4* __restrict__ o4 = (float4*)(out + (size_t)row * SEQ);
    #pragma unroll
    for (int j = 0; j < F4R; ++j) {
        float4 g;
        g.x = fminf(w[4*j+0], eNA) * r;
        g.y = fminf(w[4*j+1], eNA) * r;
        g.z = fminf(w[4*j+2], eNA) * r;
        g.w = fminf(w[4*j+3], eNA) * r;
        o4[j * 64 + lane] = g;
    }
    #pragma unroll
    for (int j = 0; j < F4L; ++j) {
        float4 t4 = lw4[j * 64 + lane];
        float4 g;
        g.x = fminf(t4.x, eNA) * r;
        g.y = fminf(t4.y, eNA) * r;
        g.z = fminf(t4.z, eNA) * r;
        g.w = fminf(t4.w, eNA) * r;
        o4[(F4R + j) * 64 + lane] = g;
    }
}

extern "C" void kernel_launch(void* const* d_in, const int* in_sizes, int n_in,
                              void* d_out, int out_size, void* d_ws, size_t ws_size,
                              hipStream_t stream) {
    const float* score = (const float*)d_in[0];
    const int*   mask  = (const int*)d_in[1];
    float*       out   = (float*)d_out;
    const int rows = in_sizes[0] / SEQ;          // 4096
    normalizer_kernel<<<rows, 64, 0, stream>>>(score, mask, out);
}